// Round 1
// baseline (296.617 us; speedup 1.0000x reference)
//
#include <hip/hip_runtime.h>
#include <stdint.h>

#define B_ 16
#define N_ 4096
#define C_ 64
#define BN_ (B_ * N_)

__device__ __forceinline__ float clipf(float x, float lo, float hi) {
    return fminf(fmaxf(x, lo), hi);
}

// ---------------------------------------------------------------------------
// Kernel 1: per-box score/cls/valid + sort key.  One 64-lane wave per box.
// ---------------------------------------------------------------------------
__global__ __launch_bounds__(256) void score_kernel(
    const float* __restrict__ proposals,      // [B,N,4]
    const float* __restrict__ preds,          // [B,N,C]
    const float* __restrict__ scores,         // [B,N]
    float* __restrict__ boxes_c,              // [B,N,4] clipped
    float* __restrict__ conf_o,               // [B,N]
    int* __restrict__ cls_o,                  // [B,N]
    unsigned char* __restrict__ valid_o,      // [B,N]
    unsigned long long* __restrict__ keys)    // [B,N]
{
    int gt   = blockIdx.x * 256 + threadIdx.x;
    int wid  = gt >> 6;          // global box id
    int lane = gt & 63;
    if (wid >= BN_) return;

    float obj = scores[wid];
    float v   = preds[(size_t)wid * C_ + lane] * obj;  // cls_conf, exact f32 mul
    int   idx = lane;
    // butterfly max-reduce, ties -> smallest index (matches jnp.argmax)
    #pragma unroll
    for (int o = 32; o > 0; o >>= 1) {
        float v2 = __shfl_xor(v, o, 64);
        int   i2 = __shfl_xor(idx, o, 64);
        if (v2 > v || (v2 == v && i2 < idx)) { v = v2; idx = i2; }
    }

    if (lane == 0) {
        float4 bx = *reinterpret_cast<const float4*>(proposals + (size_t)wid * 4);
        float x1 = clipf(bx.x, 0.f, 602.f);
        float y1 = clipf(bx.y, 0.f, 602.f);
        float x2 = clipf(bx.z, 0.f, 602.f);
        float y2 = clipf(bx.w, 0.f, 602.f);
        float ww = x2 - x1, hh = y2 - y1;
        bool valid = (obj > 0.01f) && (ww >= 5.f) && (hh >= 5.f) && (v > 0.001f);

        // composite key: conf descending, then original index ascending
        float keyf = valid ? v : -1e9f;
        unsigned int u = __float_as_uint(keyf);
        u ^= (u >> 31) ? 0xFFFFFFFFu : 0x80000000u;  // total-order flip
        int n = wid & (N_ - 1);
        keys[wid] = ((unsigned long long)u << 32) | (unsigned int)(N_ - 1 - n);

        *reinterpret_cast<float4*>(boxes_c + (size_t)wid * 4) =
            make_float4(x1, y1, x2, y2);
        conf_o[wid]  = v;
        cls_o[wid]   = idx;
        valid_o[wid] = valid ? 1 : 0;
    }
}

// ---------------------------------------------------------------------------
// Kernel 2: per-batch bitonic sort of 4096 keys (descending) + gather.
// ---------------------------------------------------------------------------
__global__ __launch_bounds__(1024) void sort_kernel(
    const unsigned long long* __restrict__ keys,
    const float* __restrict__ boxes_c,
    const float* __restrict__ conf,
    const int* __restrict__ cls,
    const unsigned char* __restrict__ valid,
    float* __restrict__ boxes_s,
    float* __restrict__ conf_s,
    int* __restrict__ cls_s,
    unsigned char* __restrict__ valid_s,
    unsigned char* __restrict__ keep)
{
    __shared__ unsigned long long k[N_];
    int b = blockIdx.x;
    // invert keys -> ascending sort == descending on originals
    for (int i = threadIdx.x; i < N_; i += 1024) k[i] = ~keys[b * N_ + i];
    __syncthreads();

    for (int len = 2; len <= N_; len <<= 1) {
        for (int j = len >> 1; j > 0; j >>= 1) {
            for (int i = threadIdx.x; i < N_; i += 1024) {
                int l = i ^ j;
                if (l > i) {
                    bool up = ((i & len) == 0);
                    unsigned long long a = k[i], d = k[l];
                    if ((a > d) == up) { k[i] = d; k[l] = a; }
                }
            }
            __syncthreads();
        }
    }

    for (int i = threadIdx.x; i < N_; i += 1024) {
        unsigned long long key = ~k[i];
        int n   = N_ - 1 - (int)(key & 0xFFFFFFFFull);
        int src = b * N_ + n;
        int dst = b * N_ + i;
        *reinterpret_cast<float4*>(boxes_s + (size_t)dst * 4) =
            *reinterpret_cast<const float4*>(boxes_c + (size_t)src * 4);
        conf_s[dst]  = conf[src];
        cls_s[dst]   = cls[src];
        valid_s[dst] = valid[src];
        keep[dst]    = 0;
    }
}

// ---------------------------------------------------------------------------
// Kernel 3: per-(batch,class) greedy NMS.  Cross-class IoU is exactly 0
// (offset 4096/class >> max coord 602), so classes are independent.
// IoU computed on OFFSET boxes to replicate the reference's fp32 rounding.
// ---------------------------------------------------------------------------
__global__ __launch_bounds__(256) void nms_kernel(
    const float* __restrict__ boxes_s,
    const int* __restrict__ cls_s,
    const unsigned char* __restrict__ valid_s,
    unsigned char* __restrict__ keep)
{
    const int b   = blockIdx.x >> 6;
    const int c   = blockIdx.x & 63;
    const int tid = threadIdx.x;

    __shared__ unsigned short list[N_];
    __shared__ unsigned int   alive[N_ / 32];
    __shared__ int            lcount;

    for (int i = tid; i < N_ / 32; i += 256) alive[i] = 0xFFFFFFFFu;

    // ordered compaction of this class's sorted positions (wave 0)
    if (tid < 64) {
        int base = 0;
        for (int it = 0; it < N_ / 64; ++it) {
            int i = it * 64 + tid;
            bool pred = (cls_s[b * N_ + i] == c) && (valid_s[b * N_ + i] != 0);
            unsigned long long m = __ballot(pred);
            if (pred) {
                int offl = __popcll(m & ((1ull << tid) - 1ull));
                list[base + offl] = (unsigned short)i;
            }
            base += __popcll(m);
        }
        if (tid == 0) lcount = base;
    }
    __syncthreads();
    const int   L    = lcount;
    const float offc = (float)c * 4096.0f;   // exact in f32

    // own boxes in registers (static indices only)
    float ox1[16], oy1[16], ox2[16], oy2[16], oar[16];
    #pragma unroll
    for (int s = 0; s < 16; ++s) {
        int j = tid + s * 256;
        if (j < L) {
            int p = list[j];
            float4 bb = *reinterpret_cast<const float4*>(
                boxes_s + (size_t)(b * N_ + p) * 4);
            ox1[s] = bb.x + offc;  oy1[s] = bb.y + offc;   // fp32 rounding as ref
            ox2[s] = bb.z + offc;  oy2[s] = bb.w + offc;
            oar[s] = fmaxf(ox2[s] - ox1[s], 0.f) * fmaxf(oy2[s] - oy1[s], 0.f);
        }
    }

    for (int k = 0; k + 1 < L; ++k) {
        __syncthreads();
        if (!((alive[k >> 5] >> (k & 31)) & 1u)) continue;   // uniform branch
        int pk = list[k];
        float4 bk = *reinterpret_cast<const float4*>(
            boxes_s + (size_t)(b * N_ + pk) * 4);
        float kx1 = bk.x + offc, ky1 = bk.y + offc;
        float kx2 = bk.z + offc, ky2 = bk.w + offc;
        float kar = fmaxf(kx2 - kx1, 0.f) * fmaxf(ky2 - ky1, 0.f);
        #pragma unroll
        for (int s = 0; s < 16; ++s) {
            int j = tid + s * 256;
            if (j > k && j < L) {
                float ltx = fmaxf(kx1, ox1[s]);
                float lty = fmaxf(ky1, oy1[s]);
                float rbx = fminf(kx2, ox2[s]);
                float rby = fminf(ky2, oy2[s]);
                float wx  = fmaxf(rbx - ltx, 0.f);
                float wy  = fmaxf(rby - lty, 0.f);
                float inter = __fmul_rn(wx, wy);                      // no FMA
                float uni   = __fsub_rn(__fadd_rn(kar, oar[s]), inter);
                float iou   = inter / __fadd_rn(uni, 1e-7f);
                if (iou > 0.2f)
                    atomicAnd(&alive[j >> 5], ~(1u << (j & 31)));
            }
        }
    }
    __syncthreads();
    for (int j = tid; j < L; j += 256) {
        if ((alive[j >> 5] >> (j & 31)) & 1u)
            keep[b * N_ + list[j]] = 1;
    }
}

// ---------------------------------------------------------------------------
// Kernel 4: write padded output: [B,N,6] then keep mask [B,N] as 0/1 floats.
// ---------------------------------------------------------------------------
__global__ __launch_bounds__(256) void write_kernel(
    const float* __restrict__ boxes_s,
    const float* __restrict__ conf_s,
    const int* __restrict__ cls_s,
    const unsigned char* __restrict__ keep,
    float* __restrict__ out)
{
    int i = blockIdx.x * 256 + threadIdx.x;
    if (i >= BN_) return;
    bool kp = keep[i] != 0;
    float4 bx = *reinterpret_cast<const float4*>(boxes_s + (size_t)i * 4);
    size_t o = (size_t)i * 6;
    out[o + 0] = kp ? bx.x : 0.f;
    out[o + 1] = kp ? bx.y : 0.f;
    out[o + 2] = kp ? bx.z : 0.f;
    out[o + 3] = kp ? bx.w : 0.f;
    out[o + 4] = kp ? conf_s[i] : 0.f;
    out[o + 5] = kp ? (float)cls_s[i] : 0.f;
    out[(size_t)BN_ * 6 + i] = kp ? 1.f : 0.f;
}

// ---------------------------------------------------------------------------
extern "C" void kernel_launch(void* const* d_in, const int* in_sizes, int n_in,
                              void* d_out, int out_size, void* d_ws, size_t ws_size,
                              hipStream_t stream) {
    (void)in_sizes; (void)n_in; (void)out_size; (void)ws_size;
    const float* proposals = (const float*)d_in[0];
    const float* preds     = (const float*)d_in[1];
    const float* scores    = (const float*)d_in[2];
    float* out = (float*)d_out;

    uint8_t* w = (uint8_t*)d_ws;
    unsigned long long* keys = (unsigned long long*)(w);            // BN*8
    float* boxes_c = (float*)(w + (size_t)BN_ * 8);                 // BN*16
    float* boxes_s = (float*)(w + (size_t)BN_ * 24);                // BN*16
    float* conf    = (float*)(w + (size_t)BN_ * 40);                // BN*4
    float* conf_s  = (float*)(w + (size_t)BN_ * 44);                // BN*4
    int*   cls     = (int*)  (w + (size_t)BN_ * 48);                // BN*4
    int*   cls_s   = (int*)  (w + (size_t)BN_ * 52);                // BN*4
    unsigned char* valid   = w + (size_t)BN_ * 56;                  // BN
    unsigned char* valid_s = w + (size_t)BN_ * 57;                  // BN
    unsigned char* keep    = w + (size_t)BN_ * 58;                  // BN

    score_kernel<<<(BN_ * 64) / 256, 256, 0, stream>>>(
        proposals, preds, scores, boxes_c, conf, cls, valid, keys);
    sort_kernel<<<B_, 1024, 0, stream>>>(
        keys, boxes_c, conf, cls, valid, boxes_s, conf_s, cls_s, valid_s, keep);
    nms_kernel<<<B_ * C_, 256, 0, stream>>>(boxes_s, cls_s, valid_s, keep);
    write_kernel<<<BN_ / 256, 256, 0, stream>>>(boxes_s, conf_s, cls_s, keep, out);
}

// Round 2
// 138.991 us; speedup vs baseline: 2.1341x; 2.1341x over previous
//
#include <hip/hip_runtime.h>
#include <stdint.h>

#define B_ 16
#define N_ 4096
#define C_ 64
#define BN_ (B_ * N_)
#define LCAP 512

__device__ __forceinline__ float clipf(float x, float lo, float hi) {
    return fminf(fmaxf(x, lo), hi);
}

// ---------------------------------------------------------------------------
// Kernel 1: per-box score/cls/valid + sort key.  One 64-lane wave per box.
// ---------------------------------------------------------------------------
__global__ __launch_bounds__(256) void score_kernel(
    const float* __restrict__ proposals,      // [B,N,4]
    const float* __restrict__ preds,          // [B,N,C]
    const float* __restrict__ scores,         // [B,N]
    float* __restrict__ boxes_c,              // [B,N,4] clipped
    float* __restrict__ conf_o,               // [B,N]
    int* __restrict__ cls_o,                  // [B,N]
    unsigned char* __restrict__ valid_o,      // [B,N]
    unsigned long long* __restrict__ keys)    // [B,N]
{
    int gt   = blockIdx.x * 256 + threadIdx.x;
    int wid  = gt >> 6;          // global box id
    int lane = gt & 63;
    if (wid >= BN_) return;

    float obj = scores[wid];
    float v   = preds[(size_t)wid * C_ + lane] * obj;  // cls_conf, exact f32 mul
    int   idx = lane;
    // butterfly max-reduce, ties -> smallest index (matches jnp.argmax)
    #pragma unroll
    for (int o = 32; o > 0; o >>= 1) {
        float v2 = __shfl_xor(v, o, 64);
        int   i2 = __shfl_xor(idx, o, 64);
        if (v2 > v || (v2 == v && i2 < idx)) { v = v2; idx = i2; }
    }

    if (lane == 0) {
        float4 bx = *reinterpret_cast<const float4*>(proposals + (size_t)wid * 4);
        float x1 = clipf(bx.x, 0.f, 602.f);
        float y1 = clipf(bx.y, 0.f, 602.f);
        float x2 = clipf(bx.z, 0.f, 602.f);
        float y2 = clipf(bx.w, 0.f, 602.f);
        float ww = x2 - x1, hh = y2 - y1;
        bool valid = (obj > 0.01f) && (ww >= 5.f) && (hh >= 5.f) && (v > 0.001f);

        // composite key: conf descending, then original index ascending
        float keyf = valid ? v : -1e9f;
        unsigned int u = __float_as_uint(keyf);
        u ^= (u >> 31) ? 0xFFFFFFFFu : 0x80000000u;  // total-order flip
        int n = wid & (N_ - 1);
        keys[wid] = ((unsigned long long)u << 32) | (unsigned int)(N_ - 1 - n);

        *reinterpret_cast<float4*>(boxes_c + (size_t)wid * 4) =
            make_float4(x1, y1, x2, y2);
        conf_o[wid]  = v;
        cls_o[wid]   = idx;
        valid_o[wid] = valid ? 1 : 0;
    }
}

// ---------------------------------------------------------------------------
// Kernel 2: per-batch bitonic sort of 4096 keys (descending) + gather.
// Writes fused cv byte (valid ? cls : 255) for cheap downstream compaction.
// ---------------------------------------------------------------------------
__global__ __launch_bounds__(1024) void sort_kernel(
    const unsigned long long* __restrict__ keys,
    const float* __restrict__ boxes_c,
    const float* __restrict__ conf,
    const int* __restrict__ cls,
    const unsigned char* __restrict__ valid,
    float* __restrict__ boxes_s,
    float* __restrict__ conf_s,
    float* __restrict__ clsf_s,
    unsigned char* __restrict__ cv_s,
    unsigned char* __restrict__ keep)
{
    __shared__ unsigned long long k[N_];
    int b = blockIdx.x;
    // invert keys -> ascending sort == descending on originals
    for (int i = threadIdx.x; i < N_; i += 1024) k[i] = ~keys[b * N_ + i];
    __syncthreads();

    for (int len = 2; len <= N_; len <<= 1) {
        for (int j = len >> 1; j > 0; j >>= 1) {
            for (int i = threadIdx.x; i < N_; i += 1024) {
                int l = i ^ j;
                if (l > i) {
                    bool up = ((i & len) == 0);
                    unsigned long long a = k[i], d = k[l];
                    if ((a > d) == up) { k[i] = d; k[l] = a; }
                }
            }
            __syncthreads();
        }
    }

    for (int i = threadIdx.x; i < N_; i += 1024) {
        unsigned long long key = ~k[i];
        int n   = N_ - 1 - (int)(key & 0xFFFFFFFFull);
        int src = b * N_ + n;
        int dst = b * N_ + i;
        *reinterpret_cast<float4*>(boxes_s + (size_t)dst * 4) =
            *reinterpret_cast<const float4*>(boxes_c + (size_t)src * 4);
        conf_s[dst]  = conf[src];
        int cl       = cls[src];
        clsf_s[dst]  = (float)cl;
        cv_s[dst]    = valid[src] ? (unsigned char)cl : (unsigned char)255;
        keep[dst]    = 0;
    }
}

// ---------------------------------------------------------------------------
// Kernel 3: per-(batch,class) ordered compaction — one wave per (b,c).
// ---------------------------------------------------------------------------
__global__ __launch_bounds__(256) void list_kernel(
    const unsigned char* __restrict__ cv_s,
    unsigned short* __restrict__ list,    // [B*C, LCAP]
    int* __restrict__ lcount)             // [B*C]
{
    int wid  = blockIdx.x * 4 + (threadIdx.x >> 6);
    int lane = threadIdx.x & 63;
    int b = wid >> 6, c = wid & 63;
    const unsigned char* cv = cv_s + (size_t)b * N_;
    unsigned short* lst = list + (size_t)wid * LCAP;
    int base = 0;
    #pragma unroll 4
    for (int it = 0; it < N_ / 64; ++it) {
        bool pred = cv[it * 64 + lane] == (unsigned char)c;
        unsigned long long m = __ballot(pred);
        if (pred) {
            int pos = base + __popcll(m & ((1ull << lane) - 1ull));
            if (pos < LCAP) lst[pos] = (unsigned short)(it * 64 + lane);
        }
        base += __popcll(m);
    }
    if (lane == 0) lcount[wid] = base;
}

// ---------------------------------------------------------------------------
// Kernel 4: per-(batch,class) greedy NMS — ONE WAVE per block, boxes in
// registers (static indexing, no spill), alive bytes + box broadcast in LDS.
// IoU on OFFSET boxes (fp32-rounded) to bit-match the reference.
// ---------------------------------------------------------------------------
template<int NS>
__device__ __forceinline__ void nms_body(
    const float* __restrict__ boxes_s,
    const unsigned short* __restrict__ lst,
    unsigned char* __restrict__ keep,
    float4* lb, unsigned char* alive8,
    int b, int L, float offc, int lane)
{
    unsigned short myp[NS];
    float x1[NS], y1[NS], x2[NS], y2[NS], ar[NS];
    bool av[NS];
    #pragma unroll
    for (int s = 0; s < NS; ++s) {
        int j = s * 64 + lane;
        bool in = j < L;
        unsigned short p = in ? lst[j] : (unsigned short)0;
        myp[s] = p;
        av[s]  = in;
        float4 bb = make_float4(0.f, 0.f, 0.f, 0.f);
        if (in) bb = *reinterpret_cast<const float4*>(
                         boxes_s + ((size_t)b * N_ + p) * 4);
        float a1 = __fadd_rn(bb.x, offc), b1 = __fadd_rn(bb.y, offc);
        float a2 = __fadd_rn(bb.z, offc), b2 = __fadd_rn(bb.w, offc);
        x1[s] = a1; y1[s] = b1; x2[s] = a2; y2[s] = b2;
        ar[s] = __fmul_rn(fmaxf(__fsub_rn(a2, a1), 0.f),
                          fmaxf(__fsub_rn(b2, b1), 0.f));
        if (in) { lb[j] = make_float4(a1, b1, a2, b2); alive8[j] = 1; }
    }
    // single wave: LDS ops are program-ordered; compiler inserts lgkmcnt waits
    for (int k = 0; k < L - 1; ++k) {
        if (!alive8[k]) continue;                 // uniform (same address)
        float4 kb = lb[k];                        // LDS broadcast
        float kar = __fmul_rn(fmaxf(__fsub_rn(kb.z, kb.x), 0.f),
                              fmaxf(__fsub_rn(kb.w, kb.y), 0.f));
        #pragma unroll
        for (int s = 0; s < NS; ++s) {
            int j = s * 64 + lane;
            if (j > k && av[s]) {
                float ltx = fmaxf(kb.x, x1[s]);
                float lty = fmaxf(kb.y, y1[s]);
                float rbx = fminf(kb.z, x2[s]);
                float rby = fminf(kb.w, y2[s]);
                float wx  = fmaxf(__fsub_rn(rbx, ltx), 0.f);
                float wy  = fmaxf(__fsub_rn(rby, lty), 0.f);
                float inter = __fmul_rn(wx, wy);
                float uni   = __fsub_rn(__fadd_rn(kar, ar[s]), inter);
                float iou   = inter / __fadd_rn(uni, 1e-7f);
                if (iou > 0.2f) { av[s] = false; alive8[j] = 0; }
            }
        }
    }
    #pragma unroll
    for (int s = 0; s < NS; ++s) {
        if (av[s]) keep[(size_t)b * N_ + myp[s]] = 1;
    }
}

__global__ __launch_bounds__(64) void nms_kernel(
    const float* __restrict__ boxes_s,
    const unsigned char* __restrict__ cv_s,
    const unsigned short* __restrict__ list,
    const int* __restrict__ lcount,
    unsigned char* __restrict__ keep)
{
    __shared__ float4 lb[LCAP];
    __shared__ unsigned char alive8[N_];
    __shared__ unsigned short flist[N_];
    int bc = blockIdx.x;
    int b = bc >> 6, c = bc & 63;
    int lane = threadIdx.x;
    int L = lcount[bc];
    float offc = (float)c * 4096.0f;              // exact in f32
    const unsigned short* lst = list + (size_t)bc * LCAP;

    if (L <= 64) {
        nms_body<1>(boxes_s, lst, keep, lb, alive8, b, L, offc, lane);
    } else if (L <= LCAP) {
        nms_body<8>(boxes_s, lst, keep, lb, alive8, b, L, offc, lane);
    } else {
        // generic fallback (never expected with this data): rebuild full list
        const unsigned char* cv = cv_s + (size_t)b * N_;
        int base = 0;
        for (int it = 0; it < N_ / 64; ++it) {
            bool pred = cv[it * 64 + lane] == (unsigned char)c;
            unsigned long long m = __ballot(pred);
            if (pred) flist[base + __popcll(m & ((1ull << lane) - 1ull))] =
                          (unsigned short)(it * 64 + lane);
            base += __popcll(m);
        }
        for (int j = lane; j < L; j += 64) alive8[j] = 1;
        for (int k = 0; k < L - 1; ++k) {
            if (!alive8[k]) continue;
            float4 kb = *reinterpret_cast<const float4*>(
                boxes_s + ((size_t)b * N_ + flist[k]) * 4);
            float kx1 = __fadd_rn(kb.x, offc), ky1 = __fadd_rn(kb.y, offc);
            float kx2 = __fadd_rn(kb.z, offc), ky2 = __fadd_rn(kb.w, offc);
            float kar = __fmul_rn(fmaxf(__fsub_rn(kx2, kx1), 0.f),
                                  fmaxf(__fsub_rn(ky2, ky1), 0.f));
            for (int j = k + 1 + lane; j < L; j += 64) {
                if (!alive8[j]) continue;
                float4 bb = *reinterpret_cast<const float4*>(
                    boxes_s + ((size_t)b * N_ + flist[j]) * 4);
                float a1 = __fadd_rn(bb.x, offc), b1 = __fadd_rn(bb.y, offc);
                float a2 = __fadd_rn(bb.z, offc), b2 = __fadd_rn(bb.w, offc);
                float arj = __fmul_rn(fmaxf(__fsub_rn(a2, a1), 0.f),
                                      fmaxf(__fsub_rn(b2, b1), 0.f));
                float ltx = fmaxf(kx1, a1), lty = fmaxf(ky1, b1);
                float rbx = fminf(kx2, a2), rby = fminf(ky2, b2);
                float wx  = fmaxf(__fsub_rn(rbx, ltx), 0.f);
                float wy  = fmaxf(__fsub_rn(rby, lty), 0.f);
                float inter = __fmul_rn(wx, wy);
                float uni   = __fsub_rn(__fadd_rn(kar, arj), inter);
                float iou   = inter / __fadd_rn(uni, 1e-7f);
                if (iou > 0.2f) alive8[j] = 0;
            }
        }
        for (int j = lane; j < L; j += 64)
            if (alive8[j]) keep[(size_t)b * N_ + flist[j]] = 1;
    }
}

// ---------------------------------------------------------------------------
// Kernel 5: write padded output: [B,N,6] then keep mask [B,N] as 0/1 floats.
// ---------------------------------------------------------------------------
__global__ __launch_bounds__(256) void write_kernel(
    const float* __restrict__ boxes_s,
    const float* __restrict__ conf_s,
    const float* __restrict__ clsf_s,
    const unsigned char* __restrict__ keep,
    float* __restrict__ out)
{
    int i = blockIdx.x * 256 + threadIdx.x;
    if (i >= BN_) return;
    bool kp = keep[i] != 0;
    float4 bx = *reinterpret_cast<const float4*>(boxes_s + (size_t)i * 4);
    size_t o = (size_t)i * 6;
    out[o + 0] = kp ? bx.x : 0.f;
    out[o + 1] = kp ? bx.y : 0.f;
    out[o + 2] = kp ? bx.z : 0.f;
    out[o + 3] = kp ? bx.w : 0.f;
    out[o + 4] = kp ? conf_s[i] : 0.f;
    out[o + 5] = kp ? clsf_s[i] : 0.f;
    out[(size_t)BN_ * 6 + i] = kp ? 1.f : 0.f;
}

// ---------------------------------------------------------------------------
extern "C" void kernel_launch(void* const* d_in, const int* in_sizes, int n_in,
                              void* d_out, int out_size, void* d_ws, size_t ws_size,
                              hipStream_t stream) {
    (void)in_sizes; (void)n_in; (void)out_size; (void)ws_size;
    const float* proposals = (const float*)d_in[0];
    const float* preds     = (const float*)d_in[1];
    const float* scores    = (const float*)d_in[2];
    float* out = (float*)d_out;

    uint8_t* w = (uint8_t*)d_ws;
    unsigned long long* keys = (unsigned long long*)(w);            // BN*8
    float* boxes_c = (float*)(w + (size_t)BN_ * 8);                 // BN*16
    float* boxes_s = (float*)(w + (size_t)BN_ * 24);                // BN*16
    float* conf    = (float*)(w + (size_t)BN_ * 40);                // BN*4
    float* conf_s  = (float*)(w + (size_t)BN_ * 44);                // BN*4
    float* clsf_s  = (float*)(w + (size_t)BN_ * 48);                // BN*4
    int*   cls     = (int*)  (w + (size_t)BN_ * 52);                // BN*4
    unsigned char* valid = w + (size_t)BN_ * 56;                    // BN
    unsigned char* cv_s  = w + (size_t)BN_ * 57;                    // BN
    unsigned char* keep  = w + (size_t)BN_ * 58;                    // BN
    unsigned short* list = (unsigned short*)(w + (size_t)BN_ * 60); // B*C*LCAP*2 = BN*16
    int* lcount          = (int*)(w + (size_t)BN_ * 76);            // B*C*4

    score_kernel<<<(BN_ * 64) / 256, 256, 0, stream>>>(
        proposals, preds, scores, boxes_c, conf, cls, valid, keys);
    sort_kernel<<<B_, 1024, 0, stream>>>(
        keys, boxes_c, conf, cls, valid, boxes_s, conf_s, clsf_s, cv_s, keep);
    list_kernel<<<(B_ * C_) / 4, 256, 0, stream>>>(cv_s, list, lcount);
    nms_kernel<<<B_ * C_, 64, 0, stream>>>(boxes_s, cv_s, list, lcount, keep);
    write_kernel<<<BN_ / 256, 256, 0, stream>>>(
        boxes_s, conf_s, clsf_s, keep, out);
}

// Round 3
// 118.511 us; speedup vs baseline: 2.5029x; 1.1728x over previous
//
#include <hip/hip_runtime.h>
#include <stdint.h>

#define B_ 16
#define N_ 4096
#define C_ 64
#define BN_ (B_ * N_)
#define LCAP 512

__device__ __forceinline__ float clipf(float x, float lo, float hi) {
    return fminf(fmaxf(x, lo), hi);
}

// ---------------------------------------------------------------------------
// Kernel 1: per-box score/cls/valid + 32-bit sort key.  One wave per box.
// key = ~flip(conf or -1e9): ascending key == conf descending; ties resolved
// by STABLE sort downstream (== jnp.argsort semantics).
// ---------------------------------------------------------------------------
__global__ __launch_bounds__(256) void score_kernel(
    const float* __restrict__ proposals,      // [B,N,4]
    const float* __restrict__ preds,          // [B,N,C]
    const float* __restrict__ scores,         // [B,N]
    unsigned int* __restrict__ key32,         // [B,N]
    float* __restrict__ conf_o,               // [B,N]
    float* __restrict__ clsf_o,               // [B,N]
    unsigned char* __restrict__ cv_o)         // [B,N] valid?cls:255
{
    int gt   = blockIdx.x * 256 + threadIdx.x;
    int wid  = gt >> 6;
    int lane = gt & 63;
    if (wid >= BN_) return;

    float obj = scores[wid];
    float v   = preds[(size_t)wid * C_ + lane] * obj;  // exact f32 mul
    int   idx = lane;
    #pragma unroll
    for (int o = 32; o > 0; o >>= 1) {   // ties -> smallest index (jnp.argmax)
        float v2 = __shfl_xor(v, o, 64);
        int   i2 = __shfl_xor(idx, o, 64);
        if (v2 > v || (v2 == v && i2 < idx)) { v = v2; idx = i2; }
    }

    if (lane == 0) {
        float4 bx = *reinterpret_cast<const float4*>(proposals + (size_t)wid * 4);
        float x1 = clipf(bx.x, 0.f, 602.f);
        float y1 = clipf(bx.y, 0.f, 602.f);
        float x2 = clipf(bx.z, 0.f, 602.f);
        float y2 = clipf(bx.w, 0.f, 602.f);
        bool valid = (obj > 0.01f) && ((x2 - x1) >= 5.f) && ((y2 - y1) >= 5.f)
                     && (v > 0.001f);
        float keyf = valid ? v : -1e9f;
        unsigned int u = __float_as_uint(keyf);
        u ^= (u >> 31) ? 0xFFFFFFFFu : 0x80000000u;   // ascending-uint == ascending-float
        key32[wid] = ~u;                               // ascending == conf DESC
        conf_o[wid] = v;
        clsf_o[wid] = (float)idx;
        cv_o[wid]   = valid ? (unsigned char)idx : (unsigned char)255;
    }
}

// ---------------------------------------------------------------------------
// Kernel 2: per-batch STABLE merge sort (1024 thr, 4 elem/thr) + gather.
// Stability: A-run takes lower_bound (strictly-less) in B; B-run takes
// upper_bound (<=) in A.  Runs always cover contiguous original-index
// ranges, so stable == original-index tie-break == reference argsort.
// ---------------------------------------------------------------------------
__global__ __launch_bounds__(1024) void sort_kernel(
    const unsigned int* __restrict__ key32,
    const float* __restrict__ proposals,
    const float* __restrict__ conf,
    const float* __restrict__ clsf,
    const unsigned char* __restrict__ cv,
    float* __restrict__ boxes_s,
    float* __restrict__ conf_s,
    float* __restrict__ clsf_s,
    unsigned char* __restrict__ cv_s,
    unsigned char* __restrict__ keep)
{
    __shared__ unsigned int  k0[N_], k1[N_];
    __shared__ unsigned short p0[N_], p1[N_];
    const int b = blockIdx.x;
    const int t = threadIdx.x;

    // --- init: load 4 contiguous keys, stable sort-4 network (composite) ---
    {
        uint4 kk = *reinterpret_cast<const uint4*>(key32 + (size_t)b * N_ + t * 4);
        unsigned int  kr[4] = {kk.x, kk.y, kk.z, kk.w};
        unsigned short pr[4] = {(unsigned short)(t * 4),     (unsigned short)(t * 4 + 1),
                                (unsigned short)(t * 4 + 2), (unsigned short)(t * 4 + 3)};
#define CE_(A, Bq)                                                              \
        {                                                                       \
            bool sw = (kr[A] > kr[Bq]) || (kr[A] == kr[Bq] && pr[A] > pr[Bq]);  \
            if (sw) {                                                           \
                unsigned int tk = kr[A]; kr[A] = kr[Bq]; kr[Bq] = tk;           \
                unsigned short tp = pr[A]; pr[A] = pr[Bq]; pr[Bq] = tp;         \
            }                                                                   \
        }
        CE_(0, 1) CE_(2, 3) CE_(0, 2) CE_(1, 3) CE_(1, 2)
#undef CE_
        #pragma unroll
        for (int s = 0; s < 4; ++s) { k0[t * 4 + s] = kr[s]; p0[t * 4 + s] = pr[s]; }
    }

    unsigned int*  ks = k0; unsigned int*  kd = k1;
    unsigned short* ps = p0; unsigned short* pd = p1;

    for (int dlog = 2; dlog <= 11; ++dlog) {
        const int R = 1 << dlog;
        __syncthreads();
        unsigned int  mk[4]; unsigned short mp[4];
        int lo[4], hi[4], sb[4], db[4]; bool teq[4];
        #pragma unroll
        for (int s = 0; s < 4; ++s) {
            int i = t + s * 1024;
            mk[s] = ks[i]; mp[s] = ps[i];
            int base = i & ~(2 * R - 1);
            bool isA = (i & R) == 0;
            sb[s] = base + (isA ? R : 0);     // sibling run base
            db[s] = base + (i & (R - 1));     // dst base (pair base + in-run idx)
            teq[s] = !isA;                    // B counts equal-A as "less" (upper_bound)
            lo[s] = -1; hi[s] = R;
        }
        for (int it = 0; it < dlog + 1; ++it) {   // lockstep: 4 searches in flight
            #pragma unroll
            for (int s = 0; s < 4; ++s) {
                if (hi[s] - lo[s] > 1) {
                    int mid = (lo[s] + hi[s]) >> 1;
                    unsigned int sk = ks[sb[s] + mid];
                    bool less = (sk < mk[s]) || (sk == mk[s] && teq[s]);
                    if (less) lo[s] = mid; else hi[s] = mid;
                }
            }
        }
        #pragma unroll
        for (int s = 0; s < 4; ++s) {   // dst buffer != src buffer: no barrier needed
            kd[db[s] + hi[s]] = mk[s];
            pd[db[s] + hi[s]] = mp[s];
        }
        unsigned int*  tk = ks; ks = kd; kd = tk;
        unsigned short* tp = ps; ps = pd; pd = tp;
    }
    __syncthreads();

    // --- gather into sorted arrays; clip boxes here (bit-identical ops) ---
    const float* prop_b = proposals + (size_t)b * N_ * 4;
    #pragma unroll
    for (int s = 0; s < 4; ++s) {
        int i   = t + s * 1024;
        int n   = ps[i];
        int src = b * N_ + n;
        int dst = b * N_ + i;
        float4 bx = *reinterpret_cast<const float4*>(prop_b + (size_t)n * 4);
        float x1 = clipf(bx.x, 0.f, 602.f);
        float y1 = clipf(bx.y, 0.f, 602.f);
        float x2 = clipf(bx.z, 0.f, 602.f);
        float y2 = clipf(bx.w, 0.f, 602.f);
        *reinterpret_cast<float4*>(boxes_s + (size_t)dst * 4) =
            make_float4(x1, y1, x2, y2);
        conf_s[dst] = conf[src];
        clsf_s[dst] = clsf[src];
        cv_s[dst]   = cv[src];
        keep[dst]   = 0;
    }
}

// ---------------------------------------------------------------------------
// Kernel 3: per-(batch,class) greedy NMS, ONE WAVE per block, list built
// in-kernel (fused).  L<=64 (~80% of blocks): pure register/shuffle loop.
// IoU on OFFSET boxes with __f*_rn to bit-match the reference.
// ---------------------------------------------------------------------------
template<int NS>
__device__ __forceinline__ void nms_body_lds(
    const float* __restrict__ boxes_s,
    const unsigned short* lst,            // LDS
    unsigned char* __restrict__ keep,
    float4* lb, unsigned char* alive8,
    int b, int L, float offc, int lane)
{
    unsigned short myp[NS];
    float x1[NS], y1[NS], x2[NS], y2[NS], ar[NS];
    bool av[NS];
    #pragma unroll
    for (int s = 0; s < NS; ++s) {
        int j = s * 64 + lane;
        bool in = j < L;
        unsigned short p = in ? lst[j] : (unsigned short)0;
        myp[s] = p; av[s] = in;
        float4 bb = make_float4(0.f, 0.f, 0.f, 0.f);
        if (in) bb = *reinterpret_cast<const float4*>(
                         boxes_s + ((size_t)b * N_ + p) * 4);
        float a1 = __fadd_rn(bb.x, offc), b1 = __fadd_rn(bb.y, offc);
        float a2 = __fadd_rn(bb.z, offc), b2 = __fadd_rn(bb.w, offc);
        x1[s] = a1; y1[s] = b1; x2[s] = a2; y2[s] = b2;
        ar[s] = __fmul_rn(fmaxf(__fsub_rn(a2, a1), 0.f),
                          fmaxf(__fsub_rn(b2, b1), 0.f));
        if (in) { lb[j] = make_float4(a1, b1, a2, b2); alive8[j] = 1; }
    }
    for (int k = 0; k < L - 1; ++k) {
        if (!alive8[k]) continue;
        float4 kb = lb[k];
        float kar = __fmul_rn(fmaxf(__fsub_rn(kb.z, kb.x), 0.f),
                              fmaxf(__fsub_rn(kb.w, kb.y), 0.f));
        #pragma unroll
        for (int s = 0; s < NS; ++s) {
            int j = s * 64 + lane;
            if (j > k && av[s]) {
                float ltx = fmaxf(kb.x, x1[s]);
                float lty = fmaxf(kb.y, y1[s]);
                float rbx = fminf(kb.z, x2[s]);
                float rby = fminf(kb.w, y2[s]);
                float wx  = fmaxf(__fsub_rn(rbx, ltx), 0.f);
                float wy  = fmaxf(__fsub_rn(rby, lty), 0.f);
                float inter = __fmul_rn(wx, wy);
                float uni   = __fsub_rn(__fadd_rn(kar, ar[s]), inter);
                float iou   = inter / __fadd_rn(uni, 1e-7f);
                if (iou > 0.2f) { av[s] = false; alive8[j] = 0; }
            }
        }
    }
    #pragma unroll
    for (int s = 0; s < NS; ++s)
        if (av[s]) keep[(size_t)b * N_ + myp[s]] = 1;
}

__global__ __launch_bounds__(64) void nms_kernel(
    const float* __restrict__ boxes_s,
    const unsigned char* __restrict__ cv_s,
    unsigned char* __restrict__ keep)
{
    __shared__ unsigned short flist[N_];
    __shared__ float4 lb[LCAP];
    __shared__ unsigned char alive8[N_];
    const int bc = blockIdx.x;
    const int b = bc >> 6, c = bc & 63;
    const int lane = threadIdx.x;
    const float offc = (float)c * 4096.0f;
    const unsigned char* cv = cv_s + (size_t)b * N_;

    // ordered ballot compaction of this class (single wave: program-ordered)
    int base = 0;
    #pragma unroll 16
    for (int it = 0; it < N_ / 64; ++it) {
        bool pred = cv[it * 64 + lane] == (unsigned char)c;
        unsigned long long m = __ballot(pred);
        if (pred)
            flist[base + __popcll(m & ((1ull << lane) - 1ull))] =
                (unsigned short)(it * 64 + lane);
        base += __popcll(m);
    }
    const int L = base;   // wave-uniform

    if (L <= 64) {
        // --- all-register greedy loop: no LDS in the chain ---
        bool av = lane < L;
        unsigned short myp = 0;
        float x1 = 0.f, y1 = 0.f, x2 = 0.f, y2 = 0.f, ar = 0.f;
        if (av) {
            myp = flist[lane];
            float4 bb = *reinterpret_cast<const float4*>(
                boxes_s + ((size_t)b * N_ + myp) * 4);
            x1 = __fadd_rn(bb.x, offc); y1 = __fadd_rn(bb.y, offc);
            x2 = __fadd_rn(bb.z, offc); y2 = __fadd_rn(bb.w, offc);
            ar = __fmul_rn(fmaxf(__fsub_rn(x2, x1), 0.f),
                           fmaxf(__fsub_rn(y2, y1), 0.f));
        }
        for (int k = 0; k < L - 1; ++k) {
            unsigned long long am = __ballot(av);
            if (!((am >> k) & 1ull)) continue;
            float kx1 = __shfl(x1, k, 64), ky1 = __shfl(y1, k, 64);
            float kx2 = __shfl(x2, k, 64), ky2 = __shfl(y2, k, 64);
            float kar = __shfl(ar, k, 64);
            if (lane > k && av) {
                float ltx = fmaxf(kx1, x1);
                float lty = fmaxf(ky1, y1);
                float rbx = fminf(kx2, x2);
                float rby = fminf(ky2, y2);
                float wx  = fmaxf(__fsub_rn(rbx, ltx), 0.f);
                float wy  = fmaxf(__fsub_rn(rby, lty), 0.f);
                float inter = __fmul_rn(wx, wy);
                float uni   = __fsub_rn(__fadd_rn(kar, ar), inter);
                float iou   = inter / __fadd_rn(uni, 1e-7f);
                if (iou > 0.2f) av = false;
            }
        }
        if (av) keep[(size_t)b * N_ + myp] = 1;
    } else if (L <= LCAP) {
        nms_body_lds<8>(boxes_s, flist, keep, lb, alive8, b, L, offc, lane);
    } else {
        // generic fallback (not expected with this data)
        for (int j = lane; j < L; j += 64) alive8[j] = 1;
        for (int k = 0; k < L - 1; ++k) {
            if (!alive8[k]) continue;
            float4 kb = *reinterpret_cast<const float4*>(
                boxes_s + ((size_t)b * N_ + flist[k]) * 4);
            float kx1 = __fadd_rn(kb.x, offc), ky1 = __fadd_rn(kb.y, offc);
            float kx2 = __fadd_rn(kb.z, offc), ky2 = __fadd_rn(kb.w, offc);
            float kar = __fmul_rn(fmaxf(__fsub_rn(kx2, kx1), 0.f),
                                  fmaxf(__fsub_rn(ky2, ky1), 0.f));
            for (int j = k + 1 + lane; j < L; j += 64) {
                if (!alive8[j]) continue;
                float4 bb = *reinterpret_cast<const float4*>(
                    boxes_s + ((size_t)b * N_ + flist[j]) * 4);
                float a1 = __fadd_rn(bb.x, offc), b1 = __fadd_rn(bb.y, offc);
                float a2 = __fadd_rn(bb.z, offc), b2 = __fadd_rn(bb.w, offc);
                float arj = __fmul_rn(fmaxf(__fsub_rn(a2, a1), 0.f),
                                      fmaxf(__fsub_rn(b2, b1), 0.f));
                float ltx = fmaxf(kx1, a1), lty = fmaxf(ky1, b1);
                float rbx = fminf(kx2, a2), rby = fminf(ky2, b2);
                float wx  = fmaxf(__fsub_rn(rbx, ltx), 0.f);
                float wy  = fmaxf(__fsub_rn(rby, lty), 0.f);
                float inter = __fmul_rn(wx, wy);
                float uni   = __fsub_rn(__fadd_rn(kar, arj), inter);
                float iou   = inter / __fadd_rn(uni, 1e-7f);
                if (iou > 0.2f) alive8[j] = 0;
            }
        }
        for (int j = lane; j < L; j += 64)
            if (alive8[j]) keep[(size_t)b * N_ + flist[j]] = 1;
    }
}

// ---------------------------------------------------------------------------
// Kernel 4: write padded output: [B,N,6] then keep mask [B,N] as 0/1 floats.
// ---------------------------------------------------------------------------
__global__ __launch_bounds__(256) void write_kernel(
    const float* __restrict__ boxes_s,
    const float* __restrict__ conf_s,
    const float* __restrict__ clsf_s,
    const unsigned char* __restrict__ keep,
    float* __restrict__ out)
{
    int i = blockIdx.x * 256 + threadIdx.x;
    if (i >= BN_) return;
    bool kp = keep[i] != 0;
    float4 bx = *reinterpret_cast<const float4*>(boxes_s + (size_t)i * 4);
    size_t o = (size_t)i * 6;
    out[o + 0] = kp ? bx.x : 0.f;
    out[o + 1] = kp ? bx.y : 0.f;
    out[o + 2] = kp ? bx.z : 0.f;
    out[o + 3] = kp ? bx.w : 0.f;
    out[o + 4] = kp ? conf_s[i] : 0.f;
    out[o + 5] = kp ? clsf_s[i] : 0.f;
    out[(size_t)BN_ * 6 + i] = kp ? 1.f : 0.f;
}

// ---------------------------------------------------------------------------
extern "C" void kernel_launch(void* const* d_in, const int* in_sizes, int n_in,
                              void* d_out, int out_size, void* d_ws, size_t ws_size,
                              hipStream_t stream) {
    (void)in_sizes; (void)n_in; (void)out_size; (void)ws_size;
    const float* proposals = (const float*)d_in[0];
    const float* preds     = (const float*)d_in[1];
    const float* scores    = (const float*)d_in[2];
    float* out = (float*)d_out;

    uint8_t* w = (uint8_t*)d_ws;
    unsigned int* key32 = (unsigned int*)(w);                       // BN*4
    float* conf    = (float*)(w + (size_t)BN_ * 4);                 // BN*4
    float* clsf    = (float*)(w + (size_t)BN_ * 8);                 // BN*4
    float* boxes_s = (float*)(w + (size_t)BN_ * 12);                // BN*16
    float* conf_s  = (float*)(w + (size_t)BN_ * 28);                // BN*4
    float* clsf_s  = (float*)(w + (size_t)BN_ * 32);                // BN*4
    unsigned char* cv   = w + (size_t)BN_ * 36;                     // BN
    unsigned char* cv_s = w + (size_t)BN_ * 37;                     // BN
    unsigned char* keep = w + (size_t)BN_ * 38;                     // BN

    score_kernel<<<(BN_ * 64) / 256, 256, 0, stream>>>(
        proposals, preds, scores, key32, conf, clsf, cv);
    sort_kernel<<<B_, 1024, 0, stream>>>(
        key32, proposals, conf, clsf, cv, boxes_s, conf_s, clsf_s, cv_s, keep);
    nms_kernel<<<B_ * C_, 64, 0, stream>>>(boxes_s, cv_s, keep);
    write_kernel<<<BN_ / 256, 256, 0, stream>>>(
        boxes_s, conf_s, clsf_s, keep, out);
}

// Round 4
// 96.209 us; speedup vs baseline: 3.0830x; 1.2318x over previous
//
#include <hip/hip_runtime.h>
#include <stdint.h>

#define B_ 16
#define N_ 4096
#define C_ 64
#define BN_ (B_ * N_)

__device__ __forceinline__ float clipf(float x, float lo, float hi) {
    return fminf(fmaxf(x, lo), hi);
}

__device__ __forceinline__ float bcastf(float v, int l) {
    return __int_as_float(__builtin_amdgcn_readlane(__float_as_int(v), l));
}
__device__ __forceinline__ unsigned long long bcast64(unsigned long long v, int l) {
    unsigned int lo = (unsigned int)__builtin_amdgcn_readlane((int)(unsigned int)v, l);
    unsigned int hi = (unsigned int)__builtin_amdgcn_readlane((int)(unsigned int)(v >> 32), l);
    return ((unsigned long long)hi << 32) | lo;
}

// IoU with reference-exact rounding (no FMA contraction); symmetric ops.
__device__ __forceinline__ float iou_rn(
    float ax1, float ay1, float ax2, float ay2, float aar,
    float bx1, float by1, float bx2, float by2, float bar)
{
    float ltx = fmaxf(ax1, bx1), lty = fmaxf(ay1, by1);
    float rbx = fminf(ax2, bx2), rby = fminf(ay2, by2);
    float wx  = fmaxf(__fsub_rn(rbx, ltx), 0.f);
    float wy  = fmaxf(__fsub_rn(rby, lty), 0.f);
    float inter = __fmul_rn(wx, wy);
    float uni   = __fsub_rn(__fadd_rn(aar, bar), inter);
    return inter / __fadd_rn(uni, 1e-7f);
}

// ---------------------------------------------------------------------------
// Kernel 1: per-box score/cls/valid + 32-bit sort key.  One wave per box.
// ---------------------------------------------------------------------------
__global__ __launch_bounds__(256) void score_kernel(
    const float* __restrict__ proposals,      // [B,N,4]
    const float* __restrict__ preds,          // [B,N,C]
    const float* __restrict__ scores,         // [B,N]
    unsigned int* __restrict__ key32,         // [B,N]
    float* __restrict__ conf_o,               // [B,N]
    float* __restrict__ clsf_o,               // [B,N]
    unsigned char* __restrict__ cv_o)         // [B,N] valid?cls:255
{
    int gt   = blockIdx.x * 256 + threadIdx.x;
    int wid  = gt >> 6;
    int lane = gt & 63;
    if (wid >= BN_) return;

    float obj = scores[wid];
    float v   = preds[(size_t)wid * C_ + lane] * obj;  // exact f32 mul
    int   idx = lane;
    #pragma unroll
    for (int o = 32; o > 0; o >>= 1) {   // ties -> smallest index (jnp.argmax)
        float v2 = __shfl_xor(v, o, 64);
        int   i2 = __shfl_xor(idx, o, 64);
        if (v2 > v || (v2 == v && i2 < idx)) { v = v2; idx = i2; }
    }

    if (lane == 0) {
        float4 bx = *reinterpret_cast<const float4*>(proposals + (size_t)wid * 4);
        float x1 = clipf(bx.x, 0.f, 602.f);
        float y1 = clipf(bx.y, 0.f, 602.f);
        float x2 = clipf(bx.z, 0.f, 602.f);
        float y2 = clipf(bx.w, 0.f, 602.f);
        bool valid = (obj > 0.01f) && ((x2 - x1) >= 5.f) && ((y2 - y1) >= 5.f)
                     && (v > 0.001f);
        float keyf = valid ? v : -1e9f;
        unsigned int u = __float_as_uint(keyf);
        u ^= (u >> 31) ? 0xFFFFFFFFu : 0x80000000u;
        key32[wid] = ~u;                               // ascending == conf DESC
        conf_o[wid] = v;
        clsf_o[wid] = (float)idx;
        cv_o[wid]   = valid ? (unsigned char)idx : (unsigned char)255;
    }
}

#define CE_(A, Bq)                                                              \
        {                                                                       \
            bool sw = (kr[A] > kr[Bq]) || (kr[A] == kr[Bq] && pr[A] > pr[Bq]);  \
            if (sw) {                                                           \
                unsigned int tk = kr[A]; kr[A] = kr[Bq]; kr[Bq] = tk;           \
                unsigned short tp = pr[A]; pr[A] = pr[Bq]; pr[Bq] = tp;         \
            }                                                                   \
        }

// ---------------------------------------------------------------------------
// Kernel 2a: 128 blocks; each stably sorts a 512-element run (LDS merge).
// ---------------------------------------------------------------------------
__global__ __launch_bounds__(128) void sortA_kernel(
    const unsigned int* __restrict__ key32,
    unsigned int* __restrict__ runkey,
    unsigned short* __restrict__ runpay)
{
    __shared__ unsigned int  k0[512], k1[512];
    __shared__ unsigned short p0[512], p1[512];
    const int blk = blockIdx.x;
    const int b = blk >> 3, c = blk & 7;
    const int t = threadIdx.x;               // 0..127
    const int g0 = b * N_ + c * 512;

    {
        uint4 kk = *reinterpret_cast<const uint4*>(key32 + g0 + t * 4);
        unsigned int  kr[4] = {kk.x, kk.y, kk.z, kk.w};
        unsigned short pr[4] = {(unsigned short)(c * 512 + t * 4),
                                (unsigned short)(c * 512 + t * 4 + 1),
                                (unsigned short)(c * 512 + t * 4 + 2),
                                (unsigned short)(c * 512 + t * 4 + 3)};
        CE_(0, 1) CE_(2, 3) CE_(0, 2) CE_(1, 3) CE_(1, 2)
        #pragma unroll
        for (int s = 0; s < 4; ++s) { k0[t * 4 + s] = kr[s]; p0[t * 4 + s] = pr[s]; }
    }

    unsigned int*  ks = k0; unsigned int*  kd = k1;
    unsigned short* ps = p0; unsigned short* pd = p1;

    for (int dlog = 2; dlog <= 8; ++dlog) {        // runs 4 -> 512
        const int R = 1 << dlog;
        __syncthreads();
        unsigned int  mk[4]; unsigned short mp[4];
        int lo[4], hi[4], sb[4], db[4]; bool teq[4];
        #pragma unroll
        for (int s = 0; s < 4; ++s) {
            int i = t + s * 128;
            mk[s] = ks[i]; mp[s] = ps[i];
            int base = i & ~(2 * R - 1);
            bool isA = (i & R) == 0;
            sb[s] = base + (isA ? R : 0);
            db[s] = base + (i & (R - 1));
            teq[s] = !isA;
            lo[s] = -1; hi[s] = R;
        }
        for (int it = 0; it < dlog + 1; ++it) {
            #pragma unroll
            for (int s = 0; s < 4; ++s) {
                if (hi[s] - lo[s] > 1) {
                    int mid = (lo[s] + hi[s]) >> 1;
                    unsigned int sk = ks[sb[s] + mid];
                    bool less = (sk < mk[s]) || (sk == mk[s] && teq[s]);
                    if (less) lo[s] = mid; else hi[s] = mid;
                }
            }
        }
        #pragma unroll
        for (int s = 0; s < 4; ++s) {
            kd[db[s] + hi[s]] = mk[s];
            pd[db[s] + hi[s]] = mp[s];
        }
        unsigned int*  tk = ks; ks = kd; kd = tk;
        unsigned short* tp = ps; ps = pd; pd = tp;
    }
    __syncthreads();
    #pragma unroll
    for (int s = 0; s < 4; ++s) {
        int i = t + s * 128;
        runkey[g0 + i] = ks[i];
        runpay[g0 + i] = ps[i];
    }
}

// ---------------------------------------------------------------------------
// Kernel 2b: per-batch final 3 merge rounds (512->4096) + gather/clip.
// ---------------------------------------------------------------------------
__global__ __launch_bounds__(1024) void sortB_kernel(
    const unsigned int* __restrict__ runkey,
    const unsigned short* __restrict__ runpay,
    const float* __restrict__ proposals,
    const float* __restrict__ conf,
    const float* __restrict__ clsf,
    const unsigned char* __restrict__ cv,
    float* __restrict__ boxes_s,
    float* __restrict__ conf_s,
    float* __restrict__ clsf_s,
    unsigned char* __restrict__ cv_s,
    unsigned char* __restrict__ keep)
{
    __shared__ unsigned int  k0[N_], k1[N_];
    __shared__ unsigned short p0[N_], p1[N_];
    const int b = blockIdx.x;
    const int t = threadIdx.x;

    #pragma unroll
    for (int s = 0; s < 4; ++s) {
        int i = t + s * 1024;
        k0[i] = runkey[b * N_ + i];
        p0[i] = runpay[b * N_ + i];
    }

    unsigned int*  ks = k0; unsigned int*  kd = k1;
    unsigned short* ps = p0; unsigned short* pd = p1;

    for (int dlog = 9; dlog <= 11; ++dlog) {       // runs 512 -> 4096
        const int R = 1 << dlog;
        __syncthreads();
        unsigned int  mk[4]; unsigned short mp[4];
        int lo[4], hi[4], sb[4], db[4]; bool teq[4];
        #pragma unroll
        for (int s = 0; s < 4; ++s) {
            int i = t + s * 1024;
            mk[s] = ks[i]; mp[s] = ps[i];
            int base = i & ~(2 * R - 1);
            bool isA = (i & R) == 0;
            sb[s] = base + (isA ? R : 0);
            db[s] = base + (i & (R - 1));
            teq[s] = !isA;
            lo[s] = -1; hi[s] = R;
        }
        for (int it = 0; it < dlog + 1; ++it) {
            #pragma unroll
            for (int s = 0; s < 4; ++s) {
                if (hi[s] - lo[s] > 1) {
                    int mid = (lo[s] + hi[s]) >> 1;
                    unsigned int sk = ks[sb[s] + mid];
                    bool less = (sk < mk[s]) || (sk == mk[s] && teq[s]);
                    if (less) lo[s] = mid; else hi[s] = mid;
                }
            }
        }
        #pragma unroll
        for (int s = 0; s < 4; ++s) {
            kd[db[s] + hi[s]] = mk[s];
            pd[db[s] + hi[s]] = mp[s];
        }
        unsigned int*  tk = ks; ks = kd; kd = tk;
        unsigned short* tp = ps; ps = pd; pd = tp;
    }
    __syncthreads();

    const float* prop_b = proposals + (size_t)b * N_ * 4;
    #pragma unroll
    for (int s = 0; s < 4; ++s) {
        int i   = t + s * 1024;
        int n   = ps[i];
        int src = b * N_ + n;
        int dst = b * N_ + i;
        float4 bx = *reinterpret_cast<const float4*>(prop_b + (size_t)n * 4);
        float x1 = clipf(bx.x, 0.f, 602.f);
        float y1 = clipf(bx.y, 0.f, 602.f);
        float x2 = clipf(bx.z, 0.f, 602.f);
        float y2 = clipf(bx.w, 0.f, 602.f);
        *reinterpret_cast<float4*>(boxes_s + (size_t)dst * 4) =
            make_float4(x1, y1, x2, y2);
        conf_s[dst] = conf[src];
        clsf_s[dst] = clsf[src];
        cv_s[dst]   = cv[src];
        keep[dst]   = 0;
    }
}

// ---------------------------------------------------------------------------
// Kernel 3: per-(batch,class) greedy NMS, one wave/block.
// Phase 1 (parallel, no loop-carried dep): suppression bit-matrix, lane k
// owns row k (bits j>k with IoU>thr).  Phase 2 (serial, cheap): bit cascade
// alive &= ~row[k] for alive k — pure readlane/and chain.
// ---------------------------------------------------------------------------
__global__ __launch_bounds__(64) void nms_kernel(
    const float* __restrict__ boxes_s,
    const unsigned char* __restrict__ cv_s,
    unsigned char* __restrict__ keep)
{
    __shared__ unsigned short flist[N_];
    __shared__ unsigned char alive8[N_];
    const int bc = blockIdx.x;
    const int b = bc >> 6, c = bc & 63;
    const int lane = threadIdx.x;
    const float offc = (float)c * 4096.0f;
    const unsigned char* cv = cv_s + (size_t)b * N_;

    // ordered ballot compaction (single wave; LDS program-ordered)
    int base = 0;
    #pragma unroll 16
    for (int it = 0; it < N_ / 64; ++it) {
        bool pred = cv[it * 64 + lane] == (unsigned char)c;
        unsigned long long m = __ballot(pred);
        if (pred)
            flist[base + __popcll(m & ((1ull << lane) - 1ull))] =
                (unsigned short)(it * 64 + lane);
        base += __popcll(m);
    }
    const int L = base;
    if (L <= 1) {
        if (lane < L) keep[(size_t)b * N_ + flist[lane]] = 1;
        return;
    }

    if (L <= 64) {
        bool in = lane < L;
        unsigned short myp = in ? flist[lane] : (unsigned short)0;
        float x1 = offc, y1 = offc, x2 = offc, y2 = offc, ar = 0.f;
        if (in) {
            float4 bb = *reinterpret_cast<const float4*>(
                boxes_s + ((size_t)b * N_ + myp) * 4);
            x1 = __fadd_rn(bb.x, offc); y1 = __fadd_rn(bb.y, offc);
            x2 = __fadd_rn(bb.z, offc); y2 = __fadd_rn(bb.w, offc);
            ar = __fmul_rn(fmaxf(__fsub_rn(x2, x1), 0.f),
                           fmaxf(__fsub_rn(y2, y1), 0.f));
        }
        // parallel bit-matrix: iterations independent -> deep pipelining
        unsigned long long row = 0;
        for (int j = 1; j < L; ++j) {
            float jx1 = bcastf(x1, j), jy1 = bcastf(y1, j);
            float jx2 = bcastf(x2, j), jy2 = bcastf(y2, j);
            float jar = bcastf(ar, j);
            float iou = iou_rn(jx1, jy1, jx2, jy2, jar, x1, y1, x2, y2, ar);
            if (in && j > lane && iou > 0.2f) row |= 1ull << j;
        }
        // serial cascade over bits
        unsigned long long alive = (L >= 64) ? ~0ull : ((1ull << L) - 1ull);
        unsigned int rlo = (unsigned int)row, rhi = (unsigned int)(row >> 32);
        for (int k = 0; k < L - 1; ++k) {
            if ((alive >> k) & 1ull) {
                unsigned int lo = (unsigned int)__builtin_amdgcn_readlane((int)rlo, k);
                unsigned int hi = (unsigned int)__builtin_amdgcn_readlane((int)rhi, k);
                alive &= ~(((unsigned long long)hi << 32) | (unsigned long long)lo);
            }
        }
        if (in && ((alive >> lane) & 1ull)) keep[(size_t)b * N_ + myp] = 1;
    } else if (L <= 128) {
        // two boxes per lane: k0=lane, k1=64+lane
        bool in1 = (64 + lane) < L;
        unsigned short myp0 = flist[lane];
        unsigned short myp1 = in1 ? flist[64 + lane] : (unsigned short)0;
        float ax1, ay1, ax2, ay2, aar;
        {
            float4 bb = *reinterpret_cast<const float4*>(
                boxes_s + ((size_t)b * N_ + myp0) * 4);
            ax1 = __fadd_rn(bb.x, offc); ay1 = __fadd_rn(bb.y, offc);
            ax2 = __fadd_rn(bb.z, offc); ay2 = __fadd_rn(bb.w, offc);
            aar = __fmul_rn(fmaxf(__fsub_rn(ax2, ax1), 0.f),
                            fmaxf(__fsub_rn(ay2, ay1), 0.f));
        }
        float bx1 = offc, by1 = offc, bx2 = offc, by2 = offc, bar = 0.f;
        if (in1) {
            float4 bb = *reinterpret_cast<const float4*>(
                boxes_s + ((size_t)b * N_ + myp1) * 4);
            bx1 = __fadd_rn(bb.x, offc); by1 = __fadd_rn(bb.y, offc);
            bx2 = __fadd_rn(bb.z, offc); by2 = __fadd_rn(bb.w, offc);
            bar = __fmul_rn(fmaxf(__fsub_rn(bx2, bx1), 0.f),
                            fmaxf(__fsub_rn(by2, by1), 0.f));
        }
        unsigned long long r0lo = 0, r0hi = 0, r1hi = 0;
        for (int j = 1; j < 64; ++j) {           // cols 1..63 (slot 0)
            float jx1 = bcastf(ax1, j), jy1 = bcastf(ay1, j);
            float jx2 = bcastf(ax2, j), jy2 = bcastf(ay2, j);
            float jar = bcastf(aar, j);
            float i0 = iou_rn(jx1, jy1, jx2, jy2, jar, ax1, ay1, ax2, ay2, aar);
            if (j > lane && i0 > 0.2f) r0lo |= 1ull << j;
        }
        const int Lh = L - 64;
        for (int jm = 0; jm < Lh; ++jm) {        // cols 64..L-1 (slot 1)
            float jx1 = bcastf(bx1, jm), jy1 = bcastf(by1, jm);
            float jx2 = bcastf(bx2, jm), jy2 = bcastf(by2, jm);
            float jar = bcastf(bar, jm);
            float i0 = iou_rn(jx1, jy1, jx2, jy2, jar, ax1, ay1, ax2, ay2, aar);
            if (i0 > 0.2f) r0hi |= 1ull << jm;   // 64+jm > lane always
            float i1 = iou_rn(jx1, jy1, jx2, jy2, jar, bx1, by1, bx2, by2, bar);
            if (in1 && jm > lane && i1 > 0.2f) r1hi |= 1ull << jm;
        }
        unsigned long long alo = ~0ull;
        unsigned long long ahi = (Lh >= 64) ? ~0ull : ((1ull << Lh) - 1ull);
        for (int k = 0; k < 64; ++k) {
            if ((alo >> k) & 1ull) {
                alo &= ~bcast64(r0lo, k);
                ahi &= ~bcast64(r0hi, k);
            }
        }
        for (int k = 0; k < Lh - 1; ++k) {
            if ((ahi >> k) & 1ull) ahi &= ~bcast64(r1hi, k);
        }
        if ((alo >> lane) & 1ull) keep[(size_t)b * N_ + myp0] = 1;
        if (in1 && ((ahi >> lane) & 1ull)) keep[(size_t)b * N_ + myp1] = 1;
    } else {
        // generic fallback (not expected with this data)
        for (int j = lane; j < L; j += 64) alive8[j] = 1;
        for (int k = 0; k < L - 1; ++k) {
            if (!alive8[k]) continue;
            float4 kb = *reinterpret_cast<const float4*>(
                boxes_s + ((size_t)b * N_ + flist[k]) * 4);
            float kx1 = __fadd_rn(kb.x, offc), ky1 = __fadd_rn(kb.y, offc);
            float kx2 = __fadd_rn(kb.z, offc), ky2 = __fadd_rn(kb.w, offc);
            float kar = __fmul_rn(fmaxf(__fsub_rn(kx2, kx1), 0.f),
                                  fmaxf(__fsub_rn(ky2, ky1), 0.f));
            for (int j = k + 1 + lane; j < L; j += 64) {
                if (!alive8[j]) continue;
                float4 bb = *reinterpret_cast<const float4*>(
                    boxes_s + ((size_t)b * N_ + flist[j]) * 4);
                float a1 = __fadd_rn(bb.x, offc), b1 = __fadd_rn(bb.y, offc);
                float a2 = __fadd_rn(bb.z, offc), b2 = __fadd_rn(bb.w, offc);
                float arj = __fmul_rn(fmaxf(__fsub_rn(a2, a1), 0.f),
                                      fmaxf(__fsub_rn(b2, b1), 0.f));
                float iou = iou_rn(kx1, ky1, kx2, ky2, kar, a1, b1, a2, b2, arj);
                if (iou > 0.2f) alive8[j] = 0;
            }
        }
        for (int j = lane; j < L; j += 64)
            if (alive8[j]) keep[(size_t)b * N_ + flist[j]] = 1;
    }
}

// ---------------------------------------------------------------------------
// Kernel 4: write padded output: [B,N,6] then keep mask [B,N] as 0/1 floats.
// ---------------------------------------------------------------------------
__global__ __launch_bounds__(256) void write_kernel(
    const float* __restrict__ boxes_s,
    const float* __restrict__ conf_s,
    const float* __restrict__ clsf_s,
    const unsigned char* __restrict__ keep,
    float* __restrict__ out)
{
    int i = blockIdx.x * 256 + threadIdx.x;
    if (i >= BN_) return;
    bool kp = keep[i] != 0;
    float4 bx = *reinterpret_cast<const float4*>(boxes_s + (size_t)i * 4);
    size_t o = (size_t)i * 6;
    out[o + 0] = kp ? bx.x : 0.f;
    out[o + 1] = kp ? bx.y : 0.f;
    out[o + 2] = kp ? bx.z : 0.f;
    out[o + 3] = kp ? bx.w : 0.f;
    out[o + 4] = kp ? conf_s[i] : 0.f;
    out[o + 5] = kp ? clsf_s[i] : 0.f;
    out[(size_t)BN_ * 6 + i] = kp ? 1.f : 0.f;
}

// ---------------------------------------------------------------------------
extern "C" void kernel_launch(void* const* d_in, const int* in_sizes, int n_in,
                              void* d_out, int out_size, void* d_ws, size_t ws_size,
                              hipStream_t stream) {
    (void)in_sizes; (void)n_in; (void)out_size; (void)ws_size;
    const float* proposals = (const float*)d_in[0];
    const float* preds     = (const float*)d_in[1];
    const float* scores    = (const float*)d_in[2];
    float* out = (float*)d_out;

    uint8_t* w = (uint8_t*)d_ws;
    unsigned int* key32    = (unsigned int*)(w);                    // BN*4
    float* conf            = (float*)(w + (size_t)BN_ * 4);         // BN*4
    float* clsf            = (float*)(w + (size_t)BN_ * 8);         // BN*4
    unsigned char* cv      = w + (size_t)BN_ * 12;                  // BN
    unsigned int* runkey   = (unsigned int*)(w + (size_t)BN_ * 13); // BN*4
    unsigned short* runpay = (unsigned short*)(w + (size_t)BN_ * 17);// BN*2
    float* boxes_s         = (float*)(w + (size_t)BN_ * 19);        // BN*16
    float* conf_s          = (float*)(w + (size_t)BN_ * 35);        // BN*4
    float* clsf_s          = (float*)(w + (size_t)BN_ * 39);        // BN*4
    unsigned char* cv_s    = w + (size_t)BN_ * 43;                  // BN
    unsigned char* keep    = w + (size_t)BN_ * 44;                  // BN

    score_kernel<<<(BN_ * 64) / 256, 256, 0, stream>>>(
        proposals, preds, scores, key32, conf, clsf, cv);
    sortA_kernel<<<128, 128, 0, stream>>>(key32, runkey, runpay);
    sortB_kernel<<<B_, 1024, 0, stream>>>(
        runkey, runpay, proposals, conf, clsf, cv,
        boxes_s, conf_s, clsf_s, cv_s, keep);
    nms_kernel<<<B_ * C_, 64, 0, stream>>>(boxes_s, cv_s, keep);
    write_kernel<<<BN_ / 256, 256, 0, stream>>>(
        boxes_s, conf_s, clsf_s, keep, out);
}